// Round 4
// baseline (44651.642 us; speedup 1.0000x reference)
//
#include <hip/hip_runtime.h>
#include <cstdint>
#include <cstddef>

// Problem constants
#define B_ 64
#define S_ 2048
#define F_ 128
#define H_ 512
#define BH (B_ * H_)
#define HO1 16777216ull
#define CO1 16809984ull
#define HO2 16842752ull
#define CO2 16875520ull

typedef __bf16 bf16_t;
typedef __attribute__((ext_vector_type(8))) __bf16 bf16x8;
typedef __attribute__((ext_vector_type(4))) float f32x4;
typedef __attribute__((ext_vector_type(8))) unsigned short u16x8;

// ---- workspace layout (bytes) ----
#define OFF_ARR   0ull        // flags: [4 groups][64 WGs] u64 (lo=wave0 epoch, hi=wave1 epoch)
#define OFF_PG    2048ull     // prev_gen0 bf16 [64][128]
#define OFF_H1    18432ull    // h1 double buffer bf16 [2][64][512]
#define OFF_H2    149504ull   // h2 double buffer bf16 [2][64][512]
#define OFF_OUT   280576ull   // fc1 'out' bf16 [64][512]
#define OFF_B1P   346112ull   // fused bias1' fp32 [512]
#define OFF_WF    348160ull   // Wfused fp32 [512][512]
#define OFF_FRAG  1396736ull  // fragment heap (9984 frags x 1KiB)
#define FR_S2   0
#define FR_S3   4096
#define FR_S1   8192
#define FR_S1T0 9472
#define FR_TOTAL 9984

__device__ __forceinline__ float sigm(float x) { return 1.f / (1.f + __expf(-x)); }
__device__ __forceinline__ float tanh_(float x) { return 2.f / (1.f + __expf(-2.f * x)) - 1.f; }

struct U128 { unsigned long long a, b; };

// fabric-coherent 16B slab load (relaxed agent atomics -> sc0 sc1, no cache fences)
__device__ __forceinline__ bf16x8 ld_slab(const bf16_t* p) {
    unsigned long long* q = (unsigned long long*)p;
    U128 u;
    u.a = __hip_atomic_load(q, __ATOMIC_RELAXED, __HIP_MEMORY_SCOPE_AGENT);
    u.b = __hip_atomic_load(q + 1, __ATOMIC_RELAXED, __HIP_MEMORY_SCOPE_AGENT);
    return __builtin_bit_cast(bf16x8, u);
}

__device__ __forceinline__ void st_bf16(bf16_t* p, float v) {
    bf16_t b = (bf16_t)v;
    __hip_atomic_store((unsigned short*)p, __builtin_bit_cast(unsigned short, b),
                       __ATOMIC_RELAXED, __HIP_MEMORY_SCOPE_AGENT);
}

// ---------------- prep: init flags + small buffers ----------------
__global__ void k_init(const float* __restrict__ pg0, const float* __restrict__ h1i,
                       const float* __restrict__ h2i, uint8_t* __restrict__ ws) {
    int idx = blockIdx.x * 256 + threadIdx.x;
    if (idx < 512) ((unsigned int*)ws)[idx] = 0u;  // flag region
    if (idx < B_ * F_) ((bf16_t*)(ws + OFF_PG))[idx] = (bf16_t)pg0[idx];
    if (idx < B_ * H_) {
        ((bf16_t*)(ws + OFF_H1))[B_ * H_ + idx] = (bf16_t)h1i[idx];  // buffer 1 = "t=-1"
        ((bf16_t*)(ws + OFF_H2))[B_ * H_ + idx] = (bf16_t)h2i[idx];
    }
}

// ---------------- prep: Wfused = W_fc1[:,128:256] @ W_fc2  (and bias1') ----------------
__global__ void k_fuse(const float* __restrict__ Wfc1, const float* __restrict__ bfc1,
                       const float* __restrict__ Wfc2, const float* __restrict__ bfc2,
                       uint8_t* __restrict__ ws) {
    int o = blockIdx.x;
    int t = threadIdx.x;
    __shared__ float wrow[128];
    wrow[t] = Wfc1[o * 256 + 128 + t];
    __syncthreads();
    float* WF = (float*)(ws + OFF_WF);
    f32x4 s = {0.f, 0.f, 0.f, 0.f};
    for (int m = 0; m < 128; ++m) {
        f32x4 b = *(const f32x4*)(Wfc2 + m * 512 + t * 4);
        float w = wrow[m];
        s[0] += w * b[0]; s[1] += w * b[1]; s[2] += w * b[2]; s[3] += w * b[3];
    }
    *(f32x4*)(WF + o * 512 + t * 4) = s;
    if (t == 0) {
        float sb = bfc1[o];
        for (int m = 0; m < 128; ++m) sb += wrow[m] * bfc2[m];
        ((float*)(ws + OFF_B1P))[o] = sb;
    }
}

// ---------------- prep: build MFMA B-fragments for all stages ----------------
__global__ void k_frags(const float* __restrict__ Wfc1, const float* __restrict__ Wih1,
                        const float* __restrict__ Whh1, const float* __restrict__ Wih2,
                        const float* __restrict__ Whh2, const float* __restrict__ Wfc2,
                        uint8_t* __restrict__ ws) {
    int gid = blockIdx.x * 256 + threadIdx.x;
    int fid = gid >> 6;
    int lane = gid & 63;
    int n16 = lane & 15, quad = lane >> 4;
    const float* WF = (const float*)(ws + OFF_WF);
    u16x8 pk;
#pragma unroll
    for (int j = 0; j < 8; ++j) {
        float v = 0.f;
        if (fid < 4096) {  // stage2 (LSTM1): in=[out|h1] K=1024
            int tl = fid & 1, ki = (fid >> 1) & 7, wv = (fid >> 4) & 3, wg = fid >> 6;
            int n32 = tl * 16 + n16; int j8 = n32 & 7; int gate = n32 >> 3;
            int R = gate * 512 + wg * 8 + j8;
            int k = wv * 256 + ki * 32 + quad * 8 + j;
            v = (k < 512) ? Wih1[R * 512 + k] : Whh1[R * 512 + k - 512];
        } else if (fid < 8192) {  // stage3 (LSTM2): in=[h1n|h2]
            int f2 = fid - 4096;
            int tl = f2 & 1, ki = (f2 >> 1) & 7, wv = (f2 >> 4) & 3, wg = f2 >> 6;
            int n32 = tl * 16 + n16; int j8 = n32 & 7; int gate = n32 >> 3;
            int R = gate * 512 + wg * 8 + j8;
            int k = wv * 256 + ki * 32 + quad * 8 + j;
            v = (k < 512) ? Wih2[R * 512 + k] : Whh2[R * 512 + k - 512];
        } else if (fid < 9472) {  // stage1 fused (t>=1): in=[x|h2p] K=640
            int f2 = fid - 8192;
            int ki = f2 % 5; int wv = (f2 / 5) & 3; int wg = f2 / 20;
            int k = wv * 160 + ki * 32 + quad * 8 + j;
            if (n16 < 8) {
                int o = wg * 8 + n16;
                v = (k < 128) ? Wfc1[o * 256 + k] : WF[o * 512 + (k - 128)];
            } else if (n16 < 10) {
                int m = wg * 2 + (n16 - 8);
                v = (k < 128) ? 0.f : Wfc2[m * 512 + (k - 128)];
            }
        } else {  // stage1 at t==0: in=[x0|prev_gen0] K=256
            int f2 = fid - 9472;
            int ki = f2 & 1; int wv = (f2 >> 1) & 3; int wg = f2 >> 3;
            int k = wv * 64 + ki * 32 + quad * 8 + j;
            if (n16 < 8) v = Wfc1[(wg * 8 + n16) * 256 + k];
        }
        bf16_t bb = (bf16_t)v;
        pk[j] = __builtin_bit_cast(unsigned short, bb);
    }
    *((u16x8*)(ws + OFF_FRAG) + (size_t)fid * 64 + lane) = pk;
}

// ---------------- wave-autonomous flag poll / LDS semaphores ----------------
__device__ __forceinline__ void flag_wait(const unsigned long long* fl, int lane, unsigned tgt) {
    while (true) {
        unsigned long long v = __hip_atomic_load((unsigned long long*)(fl + lane),
                                                 __ATOMIC_RELAXED, __HIP_MEMORY_SCOPE_AGENT);
        if (__all((int)(((unsigned)v >= tgt) && ((unsigned)(v >> 32) >= tgt)))) break;
        __builtin_amdgcn_s_sleep(1);
    }
    asm volatile("" ::: "memory");
}
__device__ __forceinline__ void sem_add(unsigned* s, int lane) {
    asm volatile("s_waitcnt lgkmcnt(0)" ::: "memory");  // own LDS writes done first
    if (lane == 0)
        __hip_atomic_fetch_add(s, 1u, __ATOMIC_RELAXED, __HIP_MEMORY_SCOPE_WORKGROUP);
}
__device__ __forceinline__ void sem_wait(unsigned* s, unsigned tgt) {
    while (__hip_atomic_load(s, __ATOMIC_RELAXED, __HIP_MEMORY_SCOPE_WORKGROUP) < tgt) {}
    asm volatile("" ::: "memory");
}

// ---------------- persistent recurrence kernel ----------------
// 256 WGs: blockIdx = g*64+wg. 4 waves/WG, fully decoupled (no __syncthreads in loop):
//   waves 0-1: critical path — fresh loads, epilogue (reduce+gates+state), stores, flags
//   waves 2-3: background — stale-operand MFMA partials, run ahead, absorb jitter
// Cross-WG: per-wave epoch flags (2/WG) over fabric. Intra-WG: red ping-pong + LDS sems.
__launch_bounds__(256, 1)
__global__ void k_rnn(const float* __restrict__ x, const float* __restrict__ c1i,
                      const float* __restrict__ c2i, const float* __restrict__ bfc1,
                      const float* __restrict__ b1, const float* __restrict__ b2g,
                      const float* __restrict__ bfc2, uint8_t* __restrict__ ws,
                      float* __restrict__ out) {
    const int wg = blockIdx.x & 63;
    const int g = blockIdx.x >> 6;
    const int tid = threadIdx.x;
    const int wave = tid >> 6, lane = tid & 63;
    const int quad = lane >> 4, row16 = lane & 15;
    const int b_ = g * 16 + row16;

    bf16_t* pg = (bf16_t*)(ws + OFF_PG);
    bf16_t* h1b = (bf16_t*)(ws + OFF_H1);
    bf16_t* h2b = (bf16_t*)(ws + OFF_H2);
    bf16_t* outb = (bf16_t*)(ws + OFF_OUT);
    const float* b1p = (const float*)(ws + OFF_B1P);
    unsigned long long* fl = (unsigned long long*)(ws + OFF_ARR) + g * 64;
    unsigned int* flu = (unsigned int*)fl;  // [wg*2 + wave] epoch slots
    const u16x8* heap = (const u16x8*)(ws + OFF_FRAG);

    // ---- weight fragments -> registers (stationary for all 2048 steps) ----
    bf16x8 fr2[16], fr3[16], fr1[5], fr10[2];
    const int wslot = wg * 4 + wave;
#pragma unroll
    for (int f = 0; f < 16; ++f)
        fr2[f] = __builtin_bit_cast(bf16x8, heap[(size_t)(FR_S2 + wslot * 16 + f) * 64 + lane]);
#pragma unroll
    for (int f = 0; f < 16; ++f)
        fr3[f] = __builtin_bit_cast(bf16x8, heap[(size_t)(FR_S3 + wslot * 16 + f) * 64 + lane]);
#pragma unroll
    for (int f = 0; f < 5; ++f)
        fr1[f] = __builtin_bit_cast(bf16x8, heap[(size_t)(FR_S1 + wslot * 5 + f) * 64 + lane]);
#pragma unroll
    for (int f = 0; f < 2; ++f)
        fr10[f] = __builtin_bit_cast(bf16x8, heap[(size_t)(FR_S1T0 + wslot * 2 + f) * 64 + lane]);

    __shared__ float red[2][4][2][16][17];  // [parity][wave][tile][row][col+pad]
    __shared__ unsigned sems[4];            // psem[2] (partials ready), rsem[2] (reads done)
    unsigned* psem = &sems[0];
    unsigned* rsem = &sems[2];
    if (tid < 4) sems[tid] = 0u;
    __syncthreads();  // only syncthreads in the kernel

    unsigned n = 0;  // hop index: P1(t)=3t, P2(t)=3t+1, P3(t)=3t+2; flag value = n+1

    if (wave < 2) {
        // ======================= CRITICAL WAVES (0,1) =======================
        const int r = tid >> 3, j = tid & 7;  // 16x8 epilogue tile (wave0: r0-7, wave1: r8-15)
        const float bi1 = b1[0 * 512 + wg * 8 + j], bf1 = b1[1 * 512 + wg * 8 + j];
        const float bg1 = b1[2 * 512 + wg * 8 + j], bo1 = b1[3 * 512 + wg * 8 + j];
        const float bi2 = b2g[0 * 512 + wg * 8 + j], bf2 = b2g[1 * 512 + wg * 8 + j];
        const float bg2 = b2g[2 * 512 + wg * 8 + j], bo2 = b2g[3 * 512 + wg * 8 + j];
        const float bias1j = b1p[wg * 8 + j];
        const float bias1t0j = bfc1[wg * 8 + j];
        const float bgen = (j < 2) ? bfc2[wg * 2 + j] : 0.f;
        float c1s = c1i[(g * 16 + r) * 512 + wg * 8 + j];
        float c2s = c2i[(g * 16 + r) * 512 + wg * 8 + j];
        bf16x8 xpre[4];

#pragma clang loop unroll(disable)
        for (int t = 0; t <= S_; ++t) {
            const int cbuf = t & 1, pbuf = cbuf ^ 1;
            // ---------- P1: out = relu([x_t | h2(t-1)] @ W1'), gen(t-1) cols ----------
            unsigned p = n & 1;
            if (t > 0) flag_wait(fl, lane, n);  // h2(t-1) visible
            {
                f32x4 acc = {0.f, 0.f, 0.f, 0.f};
                if (t == 0) {
#pragma unroll
                    for (int ki = 0; ki < 2; ++ki) {
                        int k = wave * 64 + ki * 32 + quad * 8;
                        const float* xp = x + ((size_t)b_ * S_) * F_ + k;
                        f32x4 x0 = *(const f32x4*)xp, x1 = *(const f32x4*)(xp + 4);
                        bf16x8 a;
#pragma unroll
                        for (int i = 0; i < 4; ++i) { a[i] = (bf16_t)x0[i]; a[4 + i] = (bf16_t)x1[i]; }
                        acc = __builtin_amdgcn_mfma_f32_16x16x32_bf16(a, fr10[ki], acc, 0, 0, 0);
                    }
                } else {
                    const bf16_t* h2p = h2b + (size_t)pbuf * BH + (size_t)b_ * H_;
#pragma unroll
                    for (int ki = 0; ki < 5; ++ki) {
                        int k = wave * 160 + ki * 32 + quad * 8;
                        bf16x8 a = (wave == 0 && ki < 4) ? xpre[ki] : ld_slab(h2p + (k - 128));
                        acc = __builtin_amdgcn_mfma_f32_16x16x32_bf16(a, fr1[ki], acc, 0, 0, 0);
                    }
                }
                sem_wait(&rsem[p], 2 * (n >> 1));  // red[p] reusable
#pragma unroll
                for (int i = 0; i < 4; ++i) red[p][wave][0][quad * 4 + i][row16] = acc[i];
                sem_add(&psem[p], lane);
                sem_wait(&psem[p], 4 * ((n >> 1) + 1));  // all 4 partials in
                float v = red[p][0][0][r][j] + red[p][1][0][r][j] +
                          red[p][2][0][r][j] + red[p][3][0][r][j];
                if (t < S_) {
                    float vv = fmaxf(v + (t == 0 ? bias1t0j : bias1j), 0.f);
                    st_bf16(&outb[(size_t)(g * 16 + r) * H_ + wg * 8 + j], vv);
                    asm volatile("s_waitcnt vmcnt(0)" ::: "memory");
                    if (lane == 0) __hip_atomic_store(&flu[wg * 2 + wave], n + 1,
                                                      __ATOMIC_RELAXED, __HIP_MEMORY_SCOPE_AGENT);
                }
                if (t > 0 && j < 2) {  // gen(t-1) -> d_out, off critical path
                    float vg = red[p][0][0][r][8 + j] + red[p][1][0][r][8 + j] +
                               red[p][2][0][r][8 + j] + red[p][3][0][r][8 + j] + bgen;
                    out[(size_t)(g * 16 + r) * (S_ * F_) + (size_t)(t - 1) * F_ + wg * 2 + j] = vg;
                }
                if (t == S_) break;
                sem_add(&rsem[p], lane);
            }
            n++;  // = 3t+1
            // ---------- P2: LSTM1 gates = [out(t) | h1(t-1)] @ W2 ----------
            p = n & 1;
            flag_wait(fl, lane, n);  // out(t) visible
            {
                const bf16_t* asrc = outb + (size_t)b_ * H_ + wave * 256 + quad * 8;
                bf16x8 aa[8];
#pragma unroll
                for (int ki = 0; ki < 8; ++ki) aa[ki] = ld_slab(asrc + ki * 32);
                f32x4 a0 = {0.f, 0.f, 0.f, 0.f}, a1 = {0.f, 0.f, 0.f, 0.f};
#pragma unroll
                for (int ki = 0; ki < 8; ++ki) {
                    a0 = __builtin_amdgcn_mfma_f32_16x16x32_bf16(aa[ki], fr2[ki * 2 + 0], a0, 0, 0, 0);
                    a1 = __builtin_amdgcn_mfma_f32_16x16x32_bf16(aa[ki], fr2[ki * 2 + 1], a1, 0, 0, 0);
                }
                sem_wait(&rsem[p], 2 * (n >> 1));
#pragma unroll
                for (int i = 0; i < 4; ++i) {
                    red[p][wave][0][quad * 4 + i][row16] = a0[i];
                    red[p][wave][1][quad * 4 + i][row16] = a1[i];
                }
                sem_add(&psem[p], lane);
                sem_wait(&psem[p], 4 * ((n >> 1) + 1));
                float gi = red[p][0][0][r][j] + red[p][1][0][r][j] + red[p][2][0][r][j] +
                           red[p][3][0][r][j] + bi1;
                float gf = red[p][0][0][r][j + 8] + red[p][1][0][r][j + 8] + red[p][2][0][r][j + 8] +
                           red[p][3][0][r][j + 8] + bf1;
                float gg = red[p][0][1][r][j] + red[p][1][1][r][j] + red[p][2][1][r][j] +
                           red[p][3][1][r][j] + bg1;
                float go = red[p][0][1][r][j + 8] + red[p][1][1][r][j + 8] + red[p][2][1][r][j + 8] +
                           red[p][3][1][r][j + 8] + bo1;
                float cn = sigm(gf) * c1s + sigm(gi) * tanh_(gg);
                c1s = cn;
                float h = sigm(go) * tanh_(cn);
                st_bf16(&h1b[(size_t)cbuf * BH + (size_t)(g * 16 + r) * H_ + wg * 8 + j], h);
                asm volatile("s_waitcnt vmcnt(0)" ::: "memory");
                if (lane == 0) __hip_atomic_store(&flu[wg * 2 + wave], n + 1,
                                                  __ATOMIC_RELAXED, __HIP_MEMORY_SCOPE_AGENT);
                if (t == S_ - 1) {
                    out[HO1 + (size_t)(g * 16 + r) * H_ + wg * 8 + j] = h;
                    out[CO1 + (size_t)(g * 16 + r) * H_ + wg * 8 + j] = cn;
                }
                sem_add(&rsem[p], lane);
            }
            n++;  // = 3t+2
            // ---------- P3: LSTM2 gates = [h1(t) | h2(t-1)] @ W3 ----------
            p = n & 1;
            flag_wait(fl, lane, n);  // h1(t) visible
            {
                const bf16_t* asrc = h1b + (size_t)cbuf * BH + (size_t)b_ * H_ + wave * 256 + quad * 8;
                bf16x8 aa[8];
#pragma unroll
                for (int ki = 0; ki < 8; ++ki) aa[ki] = ld_slab(asrc + ki * 32);
                f32x4 a0 = {0.f, 0.f, 0.f, 0.f}, a1 = {0.f, 0.f, 0.f, 0.f};
#pragma unroll
                for (int ki = 0; ki < 8; ++ki) {
                    a0 = __builtin_amdgcn_mfma_f32_16x16x32_bf16(aa[ki], fr3[ki * 2 + 0], a0, 0, 0, 0);
                    a1 = __builtin_amdgcn_mfma_f32_16x16x32_bf16(aa[ki], fr3[ki * 2 + 1], a1, 0, 0, 0);
                }
                sem_wait(&rsem[p], 2 * (n >> 1));
#pragma unroll
                for (int i = 0; i < 4; ++i) {
                    red[p][wave][0][quad * 4 + i][row16] = a0[i];
                    red[p][wave][1][quad * 4 + i][row16] = a1[i];
                }
                sem_add(&psem[p], lane);
                sem_wait(&psem[p], 4 * ((n >> 1) + 1));
                float gi = red[p][0][0][r][j] + red[p][1][0][r][j] + red[p][2][0][r][j] +
                           red[p][3][0][r][j] + bi2;
                float gf = red[p][0][0][r][j + 8] + red[p][1][0][r][j + 8] + red[p][2][0][r][j + 8] +
                           red[p][3][0][r][j + 8] + bf2;
                float gg = red[p][0][1][r][j] + red[p][1][1][r][j] + red[p][2][1][r][j] +
                           red[p][3][1][r][j] + bg2;
                float go = red[p][0][1][r][j + 8] + red[p][1][1][r][j + 8] + red[p][2][1][r][j + 8] +
                           red[p][3][1][r][j + 8] + bo2;
                float cn = sigm(gf) * c2s + sigm(gi) * tanh_(gg);
                c2s = cn;
                float h = sigm(go) * tanh_(cn);
                st_bf16(&h2b[(size_t)cbuf * BH + (size_t)(g * 16 + r) * H_ + wg * 8 + j], h);
                asm volatile("s_waitcnt vmcnt(0)" ::: "memory");
                if (lane == 0) __hip_atomic_store(&flu[wg * 2 + wave], n + 1,
                                                  __ATOMIC_RELAXED, __HIP_MEMORY_SCOPE_AGENT);
                if (t == S_ - 1) {
                    out[HO2 + (size_t)(g * 16 + r) * H_ + wg * 8 + j] = h;
                    out[CO2 + (size_t)(g * 16 + r) * H_ + wg * 8 + j] = cn;
                }
                sem_add(&rsem[p], lane);
            }
            n++;  // = 3t+3
            // prefetch x(t+1) while others catch up (cached loads, read-only input)
            if (wave == 0) {
                const int tn = (t + 1 < S_) ? (t + 1) : (S_ - 1);
                const float* xp = x + ((size_t)b_ * S_ + tn) * F_ + quad * 8;
#pragma unroll
                for (int ki = 0; ki < 4; ++ki) {
                    f32x4 x0 = *(const f32x4*)(xp + ki * 32);
                    f32x4 x1 = *(const f32x4*)(xp + ki * 32 + 4);
                    bf16x8 a;
#pragma unroll
                    for (int i = 0; i < 4; ++i) { a[i] = (bf16_t)x0[i]; a[4 + i] = (bf16_t)x1[i]; }
                    xpre[ki] = a;
                }
            }
        }
    } else {
        // ======================= BACKGROUND WAVES (2,3) =======================
        const int w2 = wave - 2;
        bf16x8 pre[8];
#pragma clang loop unroll(disable)
        for (int t = 0; t <= S_; ++t) {
            const int cbuf = t & 1, pbuf = cbuf ^ 1;
            unsigned p = n & 1;
            if (t > 0) flag_wait(fl, lane, n);  // h2(t-1) + everything older visible
            // P1 partial: fresh h2(t-1) K-slice (or x/pg at t==0)
            {
                f32x4 acc = {0.f, 0.f, 0.f, 0.f};
                if (t == 0) {
#pragma unroll
                    for (int ki = 0; ki < 2; ++ki) {
                        int k = wave * 64 + ki * 32 + quad * 8;  // 128..255 -> prev_gen0
                        bf16x8 a = *(const bf16x8*)(pg + (size_t)b_ * 128 + (k - 128));
                        acc = __builtin_amdgcn_mfma_f32_16x16x32_bf16(a, fr10[ki], acc, 0, 0, 0);
                    }
                } else {
                    const bf16_t* h2p = h2b + (size_t)pbuf * BH + (size_t)b_ * H_;
#pragma unroll
                    for (int ki = 0; ki < 5; ++ki) {
                        int k = wave * 160 + ki * 32 + quad * 8;
                        acc = __builtin_amdgcn_mfma_f32_16x16x32_bf16(ld_slab(h2p + (k - 128)),
                                                                      fr1[ki], acc, 0, 0, 0);
                    }
                }
                sem_wait(&rsem[p], 2 * (n >> 1));
#pragma unroll
                for (int i = 0; i < 4; ++i) red[p][wave][0][quad * 4 + i][row16] = acc[i];
                sem_add(&psem[p], lane);
            }
            if (t == S_) break;
            n++;
            // P2 partial: stale h1(t-1) (visible since flag 3t-1 <= 3t)
            p = n & 1;
            {
                const bf16_t* h1p = h1b + (size_t)pbuf * BH + (size_t)b_ * H_ + w2 * 256 + quad * 8;
#pragma unroll
                for (int ki = 0; ki < 8; ++ki) pre[ki] = ld_slab(h1p + ki * 32);
                f32x4 a0 = {0.f, 0.f, 0.f, 0.f}, a1 = {0.f, 0.f, 0.f, 0.f};
#pragma unroll
                for (int ki = 0; ki < 8; ++ki) {
                    a0 = __builtin_amdgcn_mfma_f32_16x16x32_bf16(pre[ki], fr2[ki * 2 + 0], a0, 0, 0, 0);
                    a1 = __builtin_amdgcn_mfma_f32_16x16x32_bf16(pre[ki], fr2[ki * 2 + 1], a1, 0, 0, 0);
                }
                sem_wait(&rsem[p], 2 * (n >> 1));  // gates run-ahead for parity safety
#pragma unroll
                for (int i = 0; i < 4; ++i) {
                    red[p][wave][0][quad * 4 + i][row16] = a0[i];
                    red[p][wave][1][quad * 4 + i][row16] = a1[i];
                }
                sem_add(&psem[p], lane);
            }
            n++;
            // P3 partial: stale h2(t-1)
            p = n & 1;
            {
                const bf16_t* h2s = h2b + (size_t)pbuf * BH + (size_t)b_ * H_ + w2 * 256 + quad * 8;
#pragma unroll
                for (int ki = 0; ki < 8; ++ki) pre[ki] = ld_slab(h2s + ki * 32);
                f32x4 a0 = {0.f, 0.f, 0.f, 0.f}, a1 = {0.f, 0.f, 0.f, 0.f};
#pragma unroll
                for (int ki = 0; ki < 8; ++ki) {
                    a0 = __builtin_amdgcn_mfma_f32_16x16x32_bf16(pre[ki], fr3[ki * 2 + 0], a0, 0, 0, 0);
                    a1 = __builtin_amdgcn_mfma_f32_16x16x32_bf16(pre[ki], fr3[ki * 2 + 1], a1, 0, 0, 0);
                }
                sem_wait(&rsem[p], 2 * (n >> 1));
#pragma unroll
                for (int i = 0; i < 4; ++i) {
                    red[p][wave][0][quad * 4 + i][row16] = a0[i];
                    red[p][wave][1][quad * 4 + i][row16] = a1[i];
                }
                sem_add(&psem[p], lane);
            }
            n++;
        }
    }
}

extern "C" void kernel_launch(void* const* d_in, const int* in_sizes, int n_in, void* d_out,
                              int out_size, void* d_ws, size_t ws_size, hipStream_t stream) {
    const float* x = (const float*)d_in[0];
    const float* pg0 = (const float*)d_in[1];
    const float* h1i = (const float*)d_in[2];
    const float* c1i = (const float*)d_in[3];
    const float* h2i = (const float*)d_in[4];
    const float* c2i = (const float*)d_in[5];
    const float* Wfc1 = (const float*)d_in[6];
    const float* bfc1 = (const float*)d_in[7];
    const float* Wih1 = (const float*)d_in[8];
    const float* Whh1 = (const float*)d_in[9];
    const float* b1 = (const float*)d_in[10];
    const float* Wih2 = (const float*)d_in[11];
    const float* Whh2 = (const float*)d_in[12];
    const float* b2g = (const float*)d_in[13];
    const float* Wfc2 = (const float*)d_in[14];
    const float* bfc2 = (const float*)d_in[15];
    uint8_t* ws = (uint8_t*)d_ws;
    float* out = (float*)d_out;

    k_init<<<dim3(128), dim3(256), 0, stream>>>(pg0, h1i, h2i, ws);
    k_fuse<<<dim3(512), dim3(128), 0, stream>>>(Wfc1, bfc1, Wfc2, bfc2, ws);
    k_frags<<<dim3(2496), dim3(256), 0, stream>>>(Wfc1, Wih1, Whh1, Wih2, Whh2, Wfc2, ws);
    k_rnn<<<dim3(256), dim3(256), 0, stream>>>(x, c1i, c2i, bfc1, b1, b2g, bfc2, ws, out);
}

// Round 5
// 43771.704 us; speedup vs baseline: 1.0201x; 1.0201x over previous
//
#include <hip/hip_runtime.h>
#include <cstdint>
#include <cstddef>

// Problem constants
#define B_ 64
#define S_ 2048
#define F_ 128
#define H_ 512
#define BH (B_ * H_)
#define HO1 16777216ull
#define CO1 16809984ull
#define HO2 16842752ull
#define CO2 16875520ull

typedef __bf16 bf16_t;
typedef __attribute__((ext_vector_type(8))) __bf16 bf16x8;
typedef __attribute__((ext_vector_type(4))) float f32x4;
typedef __attribute__((ext_vector_type(8))) unsigned short u16x8;

// ---- workspace layout (bytes) ----
#define OFF_ARR   0ull        // flags: [4 groups][64 WGs] u64 (lo=wave0 half, hi=wave1 half)
#define OFF_PG    2048ull     // prev_gen0 bf16 [64][128]
#define OFF_H1    18432ull    // h1 double buffer bf16 [2][64][512]
#define OFF_H2    149504ull   // h2 double buffer bf16 [2][64][512]
#define OFF_OUT   280576ull   // fc1 'out' bf16 [64][512]
#define OFF_B1P   346112ull   // fused bias1' fp32 [512]
#define OFF_WF    348160ull   // Wfused fp32 [512][512]
#define OFF_FRAG  1396736ull  // fragment heap (9984 frags x 1KiB)
#define FR_S2   0
#define FR_S3   4096
#define FR_S1   8192
#define FR_S1T0 9472
#define FR_TOTAL 9984

__device__ __forceinline__ float sigm(float x) { return 1.f / (1.f + __expf(-x)); }
__device__ __forceinline__ float tanh_(float x) { return 2.f / (1.f + __expf(-2.f * x)) - 1.f; }

struct U128 { unsigned long long a, b; };

// fabric-coherent 16B slab load (relaxed agent atomics -> sc0 sc1, no cache fences)
__device__ __forceinline__ bf16x8 ld_slab(const bf16_t* p) {
    unsigned long long* q = (unsigned long long*)p;
    U128 u;
    u.a = __hip_atomic_load(q, __ATOMIC_RELAXED, __HIP_MEMORY_SCOPE_AGENT);
    u.b = __hip_atomic_load(q + 1, __ATOMIC_RELAXED, __HIP_MEMORY_SCOPE_AGENT);
    return __builtin_bit_cast(bf16x8, u);
}

__device__ __forceinline__ void st_bf16(bf16_t* p, float v) {
    bf16_t b = (bf16_t)v;
    __hip_atomic_store((unsigned short*)p, __builtin_bit_cast(unsigned short, b),
                       __ATOMIC_RELAXED, __HIP_MEMORY_SCOPE_AGENT);
}

// ---------------- prep: init flags + small buffers ----------------
__global__ void k_init(const float* __restrict__ pg0, const float* __restrict__ h1i,
                       const float* __restrict__ h2i, uint8_t* __restrict__ ws) {
    int idx = blockIdx.x * 256 + threadIdx.x;
    if (idx < 512) ((unsigned int*)ws)[idx] = 0u;  // flag region
    if (idx < B_ * F_) ((bf16_t*)(ws + OFF_PG))[idx] = (bf16_t)pg0[idx];
    if (idx < B_ * H_) {
        ((bf16_t*)(ws + OFF_H1))[B_ * H_ + idx] = (bf16_t)h1i[idx];  // buffer 1 = "t=-1"
        ((bf16_t*)(ws + OFF_H2))[B_ * H_ + idx] = (bf16_t)h2i[idx];
    }
}

// ---------------- prep: Wfused = W_fc1[:,128:256] @ W_fc2  (and bias1') ----------------
__global__ void k_fuse(const float* __restrict__ Wfc1, const float* __restrict__ bfc1,
                       const float* __restrict__ Wfc2, const float* __restrict__ bfc2,
                       uint8_t* __restrict__ ws) {
    int o = blockIdx.x;
    int t = threadIdx.x;
    __shared__ float wrow[128];
    wrow[t] = Wfc1[o * 256 + 128 + t];
    __syncthreads();
    float* WF = (float*)(ws + OFF_WF);
    f32x4 s = {0.f, 0.f, 0.f, 0.f};
    for (int m = 0; m < 128; ++m) {
        f32x4 b = *(const f32x4*)(Wfc2 + m * 512 + t * 4);
        float w = wrow[m];
        s[0] += w * b[0]; s[1] += w * b[1]; s[2] += w * b[2]; s[3] += w * b[3];
    }
    *(f32x4*)(WF + o * 512 + t * 4) = s;
    if (t == 0) {
        float sb = bfc1[o];
        for (int m = 0; m < 128; ++m) sb += wrow[m] * bfc2[m];
        ((float*)(ws + OFF_B1P))[o] = sb;
    }
}

// ---------------- prep: build MFMA B-fragments for all stages ----------------
__global__ void k_frags(const float* __restrict__ Wfc1, const float* __restrict__ Wih1,
                        const float* __restrict__ Whh1, const float* __restrict__ Wih2,
                        const float* __restrict__ Whh2, const float* __restrict__ Wfc2,
                        uint8_t* __restrict__ ws) {
    int gid = blockIdx.x * 256 + threadIdx.x;
    int fid = gid >> 6;
    int lane = gid & 63;
    int n16 = lane & 15, quad = lane >> 4;
    const float* WF = (const float*)(ws + OFF_WF);
    u16x8 pk;
#pragma unroll
    for (int j = 0; j < 8; ++j) {
        float v = 0.f;
        if (fid < 4096) {  // stage2 (LSTM1): in=[out|h1] K=1024
            int tl = fid & 1, ki = (fid >> 1) & 7, wv = (fid >> 4) & 3, wg = fid >> 6;
            int n32 = tl * 16 + n16; int j8 = n32 & 7; int gate = n32 >> 3;
            int R = gate * 512 + wg * 8 + j8;
            int k = wv * 256 + ki * 32 + quad * 8 + j;
            v = (k < 512) ? Wih1[R * 512 + k] : Whh1[R * 512 + k - 512];
        } else if (fid < 8192) {  // stage3 (LSTM2): in=[h1n|h2]
            int f2 = fid - 4096;
            int tl = f2 & 1, ki = (f2 >> 1) & 7, wv = (f2 >> 4) & 3, wg = f2 >> 6;
            int n32 = tl * 16 + n16; int j8 = n32 & 7; int gate = n32 >> 3;
            int R = gate * 512 + wg * 8 + j8;
            int k = wv * 256 + ki * 32 + quad * 8 + j;
            v = (k < 512) ? Wih2[R * 512 + k] : Whh2[R * 512 + k - 512];
        } else if (fid < 9472) {  // stage1 fused (t>=1): in=[x|h2p] K=640
            int f2 = fid - 8192;
            int ki = f2 % 5; int wv = (f2 / 5) & 3; int wg = f2 / 20;
            int k = wv * 160 + ki * 32 + quad * 8 + j;
            if (n16 < 8) {
                int o = wg * 8 + n16;
                v = (k < 128) ? Wfc1[o * 256 + k] : WF[o * 512 + (k - 128)];
            } else if (n16 < 10) {
                int m = wg * 2 + (n16 - 8);
                v = (k < 128) ? 0.f : Wfc2[m * 512 + (k - 128)];
            }
        } else {  // stage1 at t==0: in=[x0|prev_gen0] K=256
            int f2 = fid - 9472;
            int ki = f2 & 1; int wv = (f2 >> 1) & 3; int wg = f2 >> 3;
            int k = wv * 64 + ki * 32 + quad * 8 + j;
            if (n16 < 8) v = Wfc1[(wg * 8 + n16) * 256 + k];
        }
        bf16_t bb = (bf16_t)v;
        pk[j] = __builtin_bit_cast(unsigned short, bb);
    }
    *((u16x8*)(ws + OFF_FRAG) + (size_t)fid * 64 + lane) = pk;
}

// ---------------- per-wave flag poll (u64 = both producer-wave halves) ----------------
__device__ __forceinline__ void flag_wait(const unsigned long long* fl, int lane, unsigned tgt) {
    while (true) {
        unsigned long long v = __hip_atomic_load((unsigned long long*)(fl + lane),
                                                 __ATOMIC_RELAXED, __HIP_MEMORY_SCOPE_AGENT);
        if (__all((int)(((unsigned)v >= tgt) && ((unsigned)(v >> 32) >= tgt)))) break;
    }
    asm volatile("" ::: "memory");
}

// ---------------- persistent recurrence kernel ----------------
// 256 WGs: blockIdx = g*64+wg. 4 waves/WG, ONE __syncthreads per hop.
// red is parity ping-ponged (hop&1): write red[p] -> S1 -> read red[p];
// reuse at hop+2 is ordered by S1(hop+1). Epilogue = threads 0..127 (waves 0,1);
// each epilogue wave publishes its 8 rows, drains its own stores (vmcnt 0) and
// stores its own flag half — no whole-WG arrive barrier. Waves 2,3 consume
// one-step-stale operands prefetched into registers in the post-S1 window.
__launch_bounds__(256, 1)
__global__ void k_rnn(const float* __restrict__ x, const float* __restrict__ c1i,
                      const float* __restrict__ c2i, const float* __restrict__ bfc1,
                      const float* __restrict__ b1, const float* __restrict__ b2g,
                      const float* __restrict__ bfc2, uint8_t* __restrict__ ws,
                      float* __restrict__ out) {
    const int wg = blockIdx.x & 63;
    const int g = blockIdx.x >> 6;
    const int tid = threadIdx.x;
    const int wave = tid >> 6, lane = tid & 63;
    const int quad = lane >> 4, row16 = lane & 15;
    const int b_ = g * 16 + row16;

    bf16_t* pg = (bf16_t*)(ws + OFF_PG);
    bf16_t* h1b = (bf16_t*)(ws + OFF_H1);
    bf16_t* h2b = (bf16_t*)(ws + OFF_H2);
    bf16_t* outb = (bf16_t*)(ws + OFF_OUT);
    const float* b1p = (const float*)(ws + OFF_B1P);
    unsigned long long* fl = (unsigned long long*)(ws + OFF_ARR) + g * 64;
    unsigned int* flu = (unsigned int*)fl;  // [wg*2 + epilogue-wave]
    const u16x8* heap = (const u16x8*)(ws + OFF_FRAG);

    // ---- weight fragments -> registers (stationary for all 2048 steps) ----
    bf16x8 fr2[16], fr3[16], fr1[5], fr10[2];
    const int wslot = wg * 4 + wave;
#pragma unroll
    for (int f = 0; f < 16; ++f)
        fr2[f] = __builtin_bit_cast(bf16x8, heap[(size_t)(FR_S2 + wslot * 16 + f) * 64 + lane]);
#pragma unroll
    for (int f = 0; f < 16; ++f)
        fr3[f] = __builtin_bit_cast(bf16x8, heap[(size_t)(FR_S3 + wslot * 16 + f) * 64 + lane]);
#pragma unroll
    for (int f = 0; f < 5; ++f)
        fr1[f] = __builtin_bit_cast(bf16x8, heap[(size_t)(FR_S1 + wslot * 5 + f) * 64 + lane]);
#pragma unroll
    for (int f = 0; f < 2; ++f)
        fr10[f] = __builtin_bit_cast(bf16x8, heap[(size_t)(FR_S1T0 + wslot * 2 + f) * 64 + lane]);

    __shared__ float red[2][4][2][16][17];  // [parity][wave][tile][row][col+pad]

    // epilogue-thread constants (tid<128): r = tid>>3 in 0..15, j = tid&7
    const int er = tid >> 3, ej = tid & 7;
    const float bi1 = b1[0 * 512 + wg * 8 + ej], bf1 = b1[1 * 512 + wg * 8 + ej];
    const float bg1 = b1[2 * 512 + wg * 8 + ej], bo1 = b1[3 * 512 + wg * 8 + ej];
    const float bi2 = b2g[0 * 512 + wg * 8 + ej], bf2 = b2g[1 * 512 + wg * 8 + ej];
    const float bg2 = b2g[2 * 512 + wg * 8 + ej], bo2 = b2g[3 * 512 + wg * 8 + ej];
    const float bias1j = b1p[wg * 8 + ej];
    const float bias1t0j = bfc1[wg * 8 + ej];
    const float bgen = (ej < 2) ? bfc2[wg * 2 + ej] : 0.f;
    float c1s = 0.f, c2s = 0.f;
    if (tid < 128) {
        c1s = c1i[(g * 16 + er) * 512 + wg * 8 + ej];
        c2s = c2i[(g * 16 + er) * 512 + wg * 8 + ej];
    }

    unsigned n = 0;  // hop index: P1(t)=3t, P2(t)=3t+1, P3(t)=3t+2; flag value = hop+1
    bf16x8 xpre[4];  // wave0: x(t) bf16 (K-cols ki*32 + quad*8)
    bf16x8 pre[8];   // waves 2-3: stale-operand prefetch

#pragma clang loop unroll(disable)
    for (int t = 0; t <= S_; ++t) {
        const int cbuf = t & 1, pbuf = cbuf ^ 1;

        // ================= P1: out = relu([x_t | h2(t-1)] @ W1') =================
        unsigned p = n & 1;
        if (t > 0) flag_wait(fl, lane, n);  // all waves need fresh h2(t-1)
        {
            f32x4 acc = {0.f, 0.f, 0.f, 0.f};
            if (t == 0) {
#pragma unroll
                for (int ki = 0; ki < 2; ++ki) {
                    int k = wave * 64 + ki * 32 + quad * 8;
                    bf16x8 a;
                    if (k < 128) {
                        const float* xp = x + ((size_t)b_ * S_) * F_ + k;
                        f32x4 x0 = *(const f32x4*)xp, x1 = *(const f32x4*)(xp + 4);
#pragma unroll
                        for (int i = 0; i < 4; ++i) { a[i] = (bf16_t)x0[i]; a[4 + i] = (bf16_t)x1[i]; }
                    } else {
                        a = *(const bf16x8*)(pg + (size_t)b_ * 128 + (k - 128));
                    }
                    acc = __builtin_amdgcn_mfma_f32_16x16x32_bf16(a, fr10[ki], acc, 0, 0, 0);
                }
            } else {
                const bf16_t* h2p = h2b + (size_t)pbuf * BH + (size_t)b_ * H_;
#pragma unroll
                for (int ki = 0; ki < 5; ++ki) {
                    int k = wave * 160 + ki * 32 + quad * 8;
                    bf16x8 a = (wave == 0 && ki < 4) ? xpre[ki] : ld_slab(h2p + (k - 128));
                    acc = __builtin_amdgcn_mfma_f32_16x16x32_bf16(a, fr1[ki], acc, 0, 0, 0);
                }
            }
#pragma unroll
            for (int i = 0; i < 4; ++i) red[p][wave][0][quad * 4 + i][row16] = acc[i];
        }
        __syncthreads();  // S1(3t)
        if (t == S_) {  // final: only gen(S-1) from the gen columns
            if (tid < 128 && ej < 2) {
                float vg = red[p][0][0][er][8 + ej] + red[p][1][0][er][8 + ej] +
                           red[p][2][0][er][8 + ej] + red[p][3][0][er][8 + ej] + bgen;
                out[(size_t)(g * 16 + er) * (S_ * F_) + (size_t)(S_ - 1) * F_ + wg * 2 + ej] = vg;
            }
            break;
        }
        if (wave >= 2) {  // prefetch h1(t-1) for P2 (published at flag 3t-1 < 3t)
            const bf16_t* h1p = h1b + (size_t)pbuf * BH + (size_t)b_ * H_ + (wave - 2) * 256 + quad * 8;
#pragma unroll
            for (int ki = 0; ki < 8; ++ki) pre[ki] = ld_slab(h1p + ki * 32);
        }
        if (tid < 128) {  // epilogue: out cols, publish, then gen (off-chain)
            float v = red[p][0][0][er][ej] + red[p][1][0][er][ej] +
                      red[p][2][0][er][ej] + red[p][3][0][er][ej];
            float vv = fmaxf(v + (t == 0 ? bias1t0j : bias1j), 0.f);
            st_bf16(&outb[(size_t)(g * 16 + er) * H_ + wg * 8 + ej], vv);
            asm volatile("s_waitcnt vmcnt(0)" ::: "memory");
            if (lane == 0)
                __hip_atomic_store(&flu[wg * 2 + wave], n + 1, __ATOMIC_RELAXED,
                                   __HIP_MEMORY_SCOPE_AGENT);
            if (t > 0 && ej < 2) {
                float vg = red[p][0][0][er][8 + ej] + red[p][1][0][er][8 + ej] +
                           red[p][2][0][er][8 + ej] + red[p][3][0][er][8 + ej] + bgen;
                out[(size_t)(g * 16 + er) * (S_ * F_) + (size_t)(t - 1) * F_ + wg * 2 + ej] = vg;
            }
        }
        n++;  // 3t+1
        p = n & 1;

        // ================= P2: LSTM1 gates = [out(t) | h1(t-1)] @ W2 =================
        {
            f32x4 a0 = {0.f, 0.f, 0.f, 0.f}, a1 = {0.f, 0.f, 0.f, 0.f};
            if (wave < 2) {
                flag_wait(fl, lane, n);  // out(t) fresh
                const bf16_t* asrc = outb + (size_t)b_ * H_ + wave * 256 + quad * 8;
                bf16x8 aa[8];
#pragma unroll
                for (int ki = 0; ki < 8; ++ki) aa[ki] = ld_slab(asrc + ki * 32);
#pragma unroll
                for (int ki = 0; ki < 8; ++ki) {
                    a0 = __builtin_amdgcn_mfma_f32_16x16x32_bf16(aa[ki], fr2[ki * 2 + 0], a0, 0, 0, 0);
                    a1 = __builtin_amdgcn_mfma_f32_16x16x32_bf16(aa[ki], fr2[ki * 2 + 1], a1, 0, 0, 0);
                }
            } else {
#pragma unroll
                for (int ki = 0; ki < 8; ++ki) {
                    a0 = __builtin_amdgcn_mfma_f32_16x16x32_bf16(pre[ki], fr2[ki * 2 + 0], a0, 0, 0, 0);
                    a1 = __builtin_amdgcn_mfma_f32_16x16x32_bf16(pre[ki], fr2[ki * 2 + 1], a1, 0, 0, 0);
                }
            }
#pragma unroll
            for (int i = 0; i < 4; ++i) {
                red[p][wave][0][quad * 4 + i][row16] = a0[i];
                red[p][wave][1][quad * 4 + i][row16] = a1[i];
            }
        }
        __syncthreads();  // S1(3t+1)
        if (wave >= 2) {  // prefetch h2(t-1) for P3 (published at flag 3t)
            const bf16_t* h2s = h2b + (size_t)pbuf * BH + (size_t)b_ * H_ + (wave - 2) * 256 + quad * 8;
#pragma unroll
            for (int ki = 0; ki < 8; ++ki) pre[ki] = ld_slab(h2s + ki * 32);
        }
        if (tid < 128) {
            float gi = red[p][0][0][er][ej] + red[p][1][0][er][ej] + red[p][2][0][er][ej] +
                       red[p][3][0][er][ej] + bi1;
            float gf = red[p][0][0][er][ej + 8] + red[p][1][0][er][ej + 8] +
                       red[p][2][0][er][ej + 8] + red[p][3][0][er][ej + 8] + bf1;
            float gg = red[p][0][1][er][ej] + red[p][1][1][er][ej] + red[p][2][1][er][ej] +
                       red[p][3][1][er][ej] + bg1;
            float go = red[p][0][1][er][ej + 8] + red[p][1][1][er][ej + 8] +
                       red[p][2][1][er][ej + 8] + red[p][3][1][er][ej + 8] + bo1;
            float cn = sigm(gf) * c1s + sigm(gi) * tanh_(gg);
            c1s = cn;
            float h = sigm(go) * tanh_(cn);
            st_bf16(&h1b[(size_t)cbuf * BH + (size_t)(g * 16 + er) * H_ + wg * 8 + ej], h);
            asm volatile("s_waitcnt vmcnt(0)" ::: "memory");
            if (lane == 0)
                __hip_atomic_store(&flu[wg * 2 + wave], n + 1, __ATOMIC_RELAXED,
                                   __HIP_MEMORY_SCOPE_AGENT);
            if (t == S_ - 1) {
                out[HO1 + (size_t)(g * 16 + er) * H_ + wg * 8 + ej] = h;
                out[CO1 + (size_t)(g * 16 + er) * H_ + wg * 8 + ej] = cn;
            }
        }
        n++;  // 3t+2
        p = n & 1;

        // ================= P3: LSTM2 gates = [h1(t) | h2(t-1)] @ W3 =================
        {
            f32x4 a0 = {0.f, 0.f, 0.f, 0.f}, a1 = {0.f, 0.f, 0.f, 0.f};
            if (wave < 2) {
                flag_wait(fl, lane, n);  // h1(t) fresh
                const bf16_t* asrc = h1b + (size_t)cbuf * BH + (size_t)b_ * H_ + wave * 256 + quad * 8;
                bf16x8 aa[8];
#pragma unroll
                for (int ki = 0; ki < 8; ++ki) aa[ki] = ld_slab(asrc + ki * 32);
#pragma unroll
                for (int ki = 0; ki < 8; ++ki) {
                    a0 = __builtin_amdgcn_mfma_f32_16x16x32_bf16(aa[ki], fr3[ki * 2 + 0], a0, 0, 0, 0);
                    a1 = __builtin_amdgcn_mfma_f32_16x16x32_bf16(aa[ki], fr3[ki * 2 + 1], a1, 0, 0, 0);
                }
            } else {
#pragma unroll
                for (int ki = 0; ki < 8; ++ki) {
                    a0 = __builtin_amdgcn_mfma_f32_16x16x32_bf16(pre[ki], fr3[ki * 2 + 0], a0, 0, 0, 0);
                    a1 = __builtin_amdgcn_mfma_f32_16x16x32_bf16(pre[ki], fr3[ki * 2 + 1], a1, 0, 0, 0);
                }
            }
#pragma unroll
            for (int i = 0; i < 4; ++i) {
                red[p][wave][0][quad * 4 + i][row16] = a0[i];
                red[p][wave][1][quad * 4 + i][row16] = a1[i];
            }
        }
        __syncthreads();  // S1(3t+2)
        if (tid < 128) {
            float gi = red[p][0][0][er][ej] + red[p][1][0][er][ej] + red[p][2][0][er][ej] +
                       red[p][3][0][er][ej] + bi2;
            float gf = red[p][0][0][er][ej + 8] + red[p][1][0][er][ej + 8] +
                       red[p][2][0][er][ej + 8] + red[p][3][0][er][ej + 8] + bf2;
            float gg = red[p][0][1][er][ej] + red[p][1][1][er][ej] + red[p][2][1][er][ej] +
                       red[p][3][1][er][ej] + bg2;
            float go = red[p][0][1][er][ej + 8] + red[p][1][1][er][ej + 8] +
                       red[p][2][1][er][ej + 8] + red[p][3][1][er][ej + 8] + bo2;
            float cn = sigm(gf) * c2s + sigm(gi) * tanh_(gg);
            c2s = cn;
            float h = sigm(go) * tanh_(cn);
            st_bf16(&h2b[(size_t)cbuf * BH + (size_t)(g * 16 + er) * H_ + wg * 8 + ej], h);
            asm volatile("s_waitcnt vmcnt(0)" ::: "memory");
            if (lane == 0)
                __hip_atomic_store(&flu[wg * 2 + wave], n + 1, __ATOMIC_RELAXED,
                                   __HIP_MEMORY_SCOPE_AGENT);
            if (t == S_ - 1) {
                out[HO2 + (size_t)(g * 16 + er) * H_ + wg * 8 + ej] = h;
                out[CO2 + (size_t)(g * 16 + er) * H_ + wg * 8 + ej] = cn;
            }
        }
        // wave0: prefetch x(t+1) after publishing (off-chain; gen cols ignore x at t==S_)
        if (wave == 0) {
            const int tn = (t + 1 < S_) ? (t + 1) : (S_ - 1);
            const float* xp = x + ((size_t)b_ * S_ + tn) * F_ + quad * 8;
#pragma unroll
            for (int ki = 0; ki < 4; ++ki) {
                f32x4 x0 = *(const f32x4*)(xp + ki * 32);
                f32x4 x1 = *(const f32x4*)(xp + ki * 32 + 4);
                bf16x8 a;
#pragma unroll
                for (int i = 0; i < 4; ++i) { a[i] = (bf16_t)x0[i]; a[4 + i] = (bf16_t)x1[i]; }
                xpre[ki] = a;
            }
        }
        n++;  // 3t+3
    }
}

extern "C" void kernel_launch(void* const* d_in, const int* in_sizes, int n_in, void* d_out,
                              int out_size, void* d_ws, size_t ws_size, hipStream_t stream) {
    const float* x = (const float*)d_in[0];
    const float* pg0 = (const float*)d_in[1];
    const float* h1i = (const float*)d_in[2];
    const float* c1i = (const float*)d_in[3];
    const float* h2i = (const float*)d_in[4];
    const float* c2i = (const float*)d_in[5];
    const float* Wfc1 = (const float*)d_in[6];
    const float* bfc1 = (const float*)d_in[7];
    const float* Wih1 = (const float*)d_in[8];
    const float* Whh1 = (const float*)d_in[9];
    const float* b1 = (const float*)d_in[10];
    const float* Wih2 = (const float*)d_in[11];
    const float* Whh2 = (const float*)d_in[12];
    const float* b2g = (const float*)d_in[13];
    const float* Wfc2 = (const float*)d_in[14];
    const float* bfc2 = (const float*)d_in[15];
    uint8_t* ws = (uint8_t*)d_ws;
    float* out = (float*)d_out;

    k_init<<<dim3(128), dim3(256), 0, stream>>>(pg0, h1i, h2i, ws);
    k_fuse<<<dim3(512), dim3(128), 0, stream>>>(Wfc1, bfc1, Wfc2, bfc2, ws);
    k_frags<<<dim3(2496), dim3(256), 0, stream>>>(Wfc1, Wih1, Whh1, Wih2, Whh2, Wfc2, ws);
    k_rnn<<<dim3(256), dim3(256), 0, stream>>>(x, c1i, c2i, bfc1, b1, b2g, bfc2, ws, out);
}

// Round 6
// 33446.854 us; speedup vs baseline: 1.3350x; 1.3087x over previous
//
#include <hip/hip_runtime.h>
#include <cstdint>
#include <cstddef>

// Problem constants
#define B_ 64
#define S_ 2048
#define F_ 128
#define H_ 512
#define BH (B_ * H_)
#define HO1 16777216ull
#define CO1 16809984ull
#define HO2 16842752ull
#define CO2 16875520ull

typedef __bf16 bf16_t;
typedef __attribute__((ext_vector_type(8))) __bf16 bf16x8;
typedef __attribute__((ext_vector_type(4))) float f32x4;
typedef __attribute__((ext_vector_type(8))) unsigned short u16x8;

// ---- workspace layout (bytes) ----
#define OFF_ARR   0ull        // flags: [4 groups][32 WGs][64B line]; 4 u32 quarters per WG
#define OFF_PG    8192ull     // prev_gen0 bf16 [64][128]
#define OFF_H1    24576ull    // h1 double buffer bf16 [2][64][512]
#define OFF_H2    155648ull   // h2 double buffer bf16 [2][64][512]
#define OFF_OUT   286720ull   // fc1 'out' bf16 [64][512]
#define OFF_B1P   352256ull   // fused bias1' fp32 [512]
#define OFF_WF    354304ull   // Wfused fp32 [512][512]
#define OFF_FRAG  1402880ull  // fragment heap (10752 frags x 1KiB)
// frag regions (units of 1 frag = 64 lanes * 16B)
#define FR_S2   0      // LSTM1: 128 wslots * 32 (ki*4+gate)
#define FR_S3   4096   // LSTM2: 128 wslots * 32
#define FR_S1   8192   // fc1' (t>=1): 128 wslots * 16 (ki*2+tile)
#define FR_S1T0 10240  // fc1 (t==0): 128 wslots * 4
#define FR_TOTAL 10752

__device__ __forceinline__ float sigm(float x) { return 1.f / (1.f + __expf(-x)); }
__device__ __forceinline__ float tanh_(float x) { return 2.f / (1.f + __expf(-2.f * x)) - 1.f; }

struct U128 { unsigned long long a, b; };

// fabric-coherent 16B slab load (relaxed agent atomics -> sc0 sc1, no cache fences)
__device__ __forceinline__ bf16x8 ld_slab(const bf16_t* p) {
    unsigned long long* q = (unsigned long long*)p;
    U128 u;
    u.a = __hip_atomic_load(q, __ATOMIC_RELAXED, __HIP_MEMORY_SCOPE_AGENT);
    u.b = __hip_atomic_load(q + 1, __ATOMIC_RELAXED, __HIP_MEMORY_SCOPE_AGENT);
    return __builtin_bit_cast(bf16x8, u);
}

__device__ __forceinline__ void st_bf16(bf16_t* p, float v) {
    bf16_t b = (bf16_t)v;
    __hip_atomic_store((unsigned short*)p, __builtin_bit_cast(unsigned short, b),
                       __ATOMIC_RELAXED, __HIP_MEMORY_SCOPE_AGENT);
}

// ---------------- prep: init flags + small buffers ----------------
__global__ void k_init(const float* __restrict__ pg0, const float* __restrict__ h1i,
                       const float* __restrict__ h2i, uint8_t* __restrict__ ws) {
    int idx = blockIdx.x * 256 + threadIdx.x;
    if (idx < 2048) ((unsigned int*)ws)[idx] = 0u;  // padded flag region
    if (idx < B_ * F_) ((bf16_t*)(ws + OFF_PG))[idx] = (bf16_t)pg0[idx];
    if (idx < B_ * H_) {
        ((bf16_t*)(ws + OFF_H1))[B_ * H_ + idx] = (bf16_t)h1i[idx];  // buffer 1 = "t=-1"
        ((bf16_t*)(ws + OFF_H2))[B_ * H_ + idx] = (bf16_t)h2i[idx];
    }
}

// ---------------- prep: Wfused = W_fc1[:,128:256] @ W_fc2  (and bias1') ----------------
__global__ void k_fuse(const float* __restrict__ Wfc1, const float* __restrict__ bfc1,
                       const float* __restrict__ Wfc2, const float* __restrict__ bfc2,
                       uint8_t* __restrict__ ws) {
    int o = blockIdx.x;
    int t = threadIdx.x;
    __shared__ float wrow[128];
    wrow[t] = Wfc1[o * 256 + 128 + t];
    __syncthreads();
    float* WF = (float*)(ws + OFF_WF);
    f32x4 s = {0.f, 0.f, 0.f, 0.f};
    for (int m = 0; m < 128; ++m) {
        f32x4 b = *(const f32x4*)(Wfc2 + m * 512 + t * 4);
        float w = wrow[m];
        s[0] += w * b[0]; s[1] += w * b[1]; s[2] += w * b[2]; s[3] += w * b[3];
    }
    *(f32x4*)(WF + o * 512 + t * 4) = s;
    if (t == 0) {
        float sb = bfc1[o];
        for (int m = 0; m < 128; ++m) sb += wrow[m] * bfc2[m];
        ((float*)(ws + OFF_B1P))[o] = sb;
    }
}

// ---------------- prep: build MFMA B-fragments (16 cols/WG layout) ----------------
// Frag element convention (verified rounds 1-5): lane=(n16,quad), elem j:
// value = W[colbase + n16][kbase + quad*8 + j].
__global__ void k_frags(const float* __restrict__ Wfc1, const float* __restrict__ Wih1,
                        const float* __restrict__ Whh1, const float* __restrict__ Wih2,
                        const float* __restrict__ Whh2, const float* __restrict__ Wfc2,
                        uint8_t* __restrict__ ws) {
    int gid = blockIdx.x * 256 + threadIdx.x;  // FR_TOTAL*64 threads
    int fid = gid >> 6;
    int lane = gid & 63;
    int n16 = lane & 15, quad = lane >> 4;
    const float* WF = (const float*)(ws + OFF_WF);
    u16x8 pk;
#pragma unroll
    for (int j = 0; j < 8; ++j) {
        float v = 0.f;
        if (fid < 8192) {  // S2/S3: K=1024 [fresh 512 | stale 512], 4 gate-tiles of 16 cols
            int f2 = fid & 4095;
            const float* Wih = (fid < 4096) ? Wih1 : Wih2;
            const float* Whh = (fid < 4096) ? Whh1 : Whh2;
            int wslot = f2 >> 5, r = f2 & 31;
            int ki = r >> 2, gate = r & 3;
            int wg = wslot >> 2, wave = wslot & 3;
            int R = gate * 512 + wg * 16 + n16;
            int k = wave * 256 + ki * 32 + quad * 8 + j;
            v = (k < 512) ? Wih[R * 512 + k] : Whh[R * 512 + k - 512];
        } else if (fid < 10240) {  // S1 (t>=1): K=640 [x 128 | h2 512]; tiles: out(16)/gen(4)
            int f2 = fid - 8192;
            int wslot = f2 >> 4, r = f2 & 15;
            int ki = r >> 1, tile = r & 1;
            int wg = wslot >> 2, wave = wslot & 3;
            int K; bool valid;
            if (wave < 2) { K = 128 + wave * 256 + ki * 32 + quad * 8 + j; valid = true; }
            else { K = (wave - 2) * 64 + ki * 32 + quad * 8 + j; valid = (ki < 2); }
            if (valid) {
                if (tile == 0) {
                    int o = wg * 16 + n16;
                    v = (K < 128) ? Wfc1[o * 256 + K] : WF[o * 512 + (K - 128)];
                } else if (n16 < 4) {
                    int m = wg * 4 + n16;
                    v = (K >= 128) ? Wfc2[m * 512 + (K - 128)] : 0.f;
                }
            }
        } else {  // S1T0 (t==0): K=256 [x 128 | pg 128]; tile0 out, tile1 zero
            int f2 = fid - 10240;
            int wslot = f2 >> 2, r = f2 & 3;
            int ki = r >> 1, tile = r & 1;
            int wg = wslot >> 2, wave = wslot & 3;
            int K = (wave < 2) ? (128 + wave * 64 + ki * 32 + quad * 8 + j)
                               : ((wave - 2) * 64 + ki * 32 + quad * 8 + j);
            if (tile == 0) v = Wfc1[(wg * 16 + n16) * 256 + K];
        }
        bf16_t bb = (bf16_t)v;
        pk[j] = __builtin_bit_cast(unsigned short, bb);
    }
    *((u16x8*)(ws + OFF_FRAG) + (size_t)fid * 64 + lane) = pk;
}

// ---------------- padded-flag poll (only waves 0-1 ever call this) ----------------
// Group flag region: 32 WGs x 64B line; quarters fb[wg*16 + wave] (u32).
__device__ __forceinline__ void flag_wait(const unsigned int* fb, int lane, unsigned tgt) {
    const unsigned long long* q = (const unsigned long long*)fb;
    const bool act = lane < 32;
    const int w8 = lane * 8;
    while (true) {
        bool ok = true;
        if (act) {
            unsigned long long a = __hip_atomic_load((unsigned long long*)(q + w8),
                                                     __ATOMIC_RELAXED, __HIP_MEMORY_SCOPE_AGENT);
            unsigned long long b = __hip_atomic_load((unsigned long long*)(q + w8 + 1),
                                                     __ATOMIC_RELAXED, __HIP_MEMORY_SCOPE_AGENT);
            ok = ((unsigned)a >= tgt) && ((unsigned)(a >> 32) >= tgt) &&
                 ((unsigned)b >= tgt) && ((unsigned)(b >> 32) >= tgt);
        }
        if (__all((int)ok)) break;
    }
    asm volatile("" ::: "memory");
}

// ---------------- persistent recurrence kernel ----------------
// 128 WGs: blockIdx = g*32+wg (4 batch-groups x 32 col-groups of 16 cols).
// One __syncthreads per hop. Per-wave flag quarters. Only waves 0-1 poll:
// P1 K-split gives waves 2-3 the x-columns (no flag dependency); P2/P3 give
// them the stale halves (visibility transitively guaranteed by waves 0-1's
// poll happening before the shared barrier). c1/c2 live in registers
// (256 threads = 16 rows x 16 cols per WG).
__launch_bounds__(256, 1)
__global__ void k_rnn(const float* __restrict__ x, const float* __restrict__ c1i,
                      const float* __restrict__ c2i, const float* __restrict__ bfc1,
                      const float* __restrict__ b1, const float* __restrict__ b2g,
                      const float* __restrict__ bfc2, uint8_t* __restrict__ ws,
                      float* __restrict__ out) {
    const int wg = blockIdx.x & 31;
    const int g = blockIdx.x >> 5;
    const int tid = threadIdx.x;
    const int wave = tid >> 6, lane = tid & 63;
    const int quad = lane >> 4, row16 = lane & 15;
    const int b_ = g * 16 + row16;

    bf16_t* pg = (bf16_t*)(ws + OFF_PG);
    bf16_t* h1b = (bf16_t*)(ws + OFF_H1);
    bf16_t* h2b = (bf16_t*)(ws + OFF_H2);
    bf16_t* outb = (bf16_t*)(ws + OFF_OUT);
    const float* b1p = (const float*)(ws + OFF_B1P);
    unsigned int* fb = (unsigned int*)(ws + OFF_ARR) + g * 512;  // 2KB per group
    const u16x8* heap = (const u16x8*)(ws + OFF_FRAG);

    // ---- weight fragments -> registers (stationary for all 2048 steps) ----
    bf16x8 fr2[32], fr3[32], fr1[16], fr10[4];
    const int wslot = wg * 4 + wave;
#pragma unroll
    for (int f = 0; f < 32; ++f)
        fr2[f] = __builtin_bit_cast(bf16x8, heap[(size_t)(FR_S2 + wslot * 32 + f) * 64 + lane]);
#pragma unroll
    for (int f = 0; f < 32; ++f)
        fr3[f] = __builtin_bit_cast(bf16x8, heap[(size_t)(FR_S3 + wslot * 32 + f) * 64 + lane]);
#pragma unroll
    for (int f = 0; f < 16; ++f)
        fr1[f] = __builtin_bit_cast(bf16x8, heap[(size_t)(FR_S1 + wslot * 16 + f) * 64 + lane]);
#pragma unroll
    for (int f = 0; f < 4; ++f)
        fr10[f] = __builtin_bit_cast(bf16x8, heap[(size_t)(FR_S1T0 + wslot * 4 + f) * 64 + lane]);

    __shared__ float red[2][4][4][16][17];  // [parity][wave][tile/gate][row][col+pad]

    // epilogue mapping: row = tid>>4 (wave w owns rows 4w..4w+3), j = tid&15
    const int er = tid >> 4, ej = tid & 15;
    const float bi1 = b1[0 * 512 + wg * 16 + ej], bf1 = b1[1 * 512 + wg * 16 + ej];
    const float bg1 = b1[2 * 512 + wg * 16 + ej], bo1 = b1[3 * 512 + wg * 16 + ej];
    const float bi2 = b2g[0 * 512 + wg * 16 + ej], bf2 = b2g[1 * 512 + wg * 16 + ej];
    const float bg2 = b2g[2 * 512 + wg * 16 + ej], bo2 = b2g[3 * 512 + wg * 16 + ej];
    const float bias1j = b1p[wg * 16 + ej];
    const float bias1t0j = bfc1[wg * 16 + ej];
    const float bgen = (ej < 4) ? bfc2[wg * 4 + ej] : 0.f;
    float c1s = c1i[(g * 16 + er) * 512 + wg * 16 + ej];
    float c2s = c2i[(g * 16 + er) * 512 + wg * 16 + ej];

    bf16x8 xpre[2];  // waves 2-3: x(t) cols (wave-2)*64 + ki*32 + quad*8
    bf16x8 pre[8];   // waves 2-3: stale-operand slabs

#pragma clang loop unroll(disable)
    for (int t = 0; t <= S_; ++t) {
        const int cbuf = t & 1, pbuf = cbuf ^ 1;
        const int p1 = t & 1, p2 = p1 ^ 1, p3 = p1;
        const unsigned n3t = 3u * (unsigned)t;

        // ================= P1 MFMA: out|gen = [x_t | h2(t-1)] @ W1' =================
        {
            f32x4 a0 = {0.f, 0.f, 0.f, 0.f}, a1 = {0.f, 0.f, 0.f, 0.f};
            if (wave < 2) {
                if (t > 0) flag_wait(fb, lane, n3t);  // h2(t-1) fresh
                if (t == 0) {
#pragma unroll
                    for (int ki = 0; ki < 2; ++ki) {
                        bf16x8 a = *(const bf16x8*)(pg + (size_t)b_ * 128 + wave * 64 + ki * 32 + quad * 8);
                        a0 = __builtin_amdgcn_mfma_f32_16x16x32_bf16(a, fr10[ki * 2 + 0], a0, 0, 0, 0);
                        a1 = __builtin_amdgcn_mfma_f32_16x16x32_bf16(a, fr10[ki * 2 + 1], a1, 0, 0, 0);
                    }
                } else {
                    const bf16_t* h2p = h2b + (size_t)pbuf * BH + (size_t)b_ * H_ + wave * 256 + quad * 8;
#pragma unroll
                    for (int ki = 0; ki < 8; ++ki) {
                        bf16x8 a = ld_slab(h2p + ki * 32);
                        a0 = __builtin_amdgcn_mfma_f32_16x16x32_bf16(a, fr1[ki * 2 + 0], a0, 0, 0, 0);
                        a1 = __builtin_amdgcn_mfma_f32_16x16x32_bf16(a, fr1[ki * 2 + 1], a1, 0, 0, 0);
                    }
                }
            } else {
                if (t == 0) {
#pragma unroll
                    for (int ki = 0; ki < 2; ++ki) {
                        const float* xp = x + (size_t)b_ * S_ * F_ + (wave - 2) * 64 + ki * 32 + quad * 8;
                        f32x4 x0 = *(const f32x4*)xp, x1 = *(const f32x4*)(xp + 4);
                        bf16x8 a;
#pragma unroll
                        for (int i = 0; i < 4; ++i) { a[i] = (bf16_t)x0[i]; a[4 + i] = (bf16_t)x1[i]; }
                        a0 = __builtin_amdgcn_mfma_f32_16x16x32_bf16(a, fr10[ki * 2 + 0], a0, 0, 0, 0);
                        a1 = __builtin_amdgcn_mfma_f32_16x16x32_bf16(a, fr10[ki * 2 + 1], a1, 0, 0, 0);
                    }
                } else {
#pragma unroll
                    for (int ki = 0; ki < 2; ++ki) {
                        a0 = __builtin_amdgcn_mfma_f32_16x16x32_bf16(xpre[ki], fr1[ki * 2 + 0], a0, 0, 0, 0);
                        a1 = __builtin_amdgcn_mfma_f32_16x16x32_bf16(xpre[ki], fr1[ki * 2 + 1], a1, 0, 0, 0);
                    }
                }
            }
#pragma unroll
            for (int i = 0; i < 4; ++i) {
                red[p1][wave][0][quad * 4 + i][row16] = a0[i];
                red[p1][wave][1][quad * 4 + i][row16] = a1[i];
            }
        }
        __syncthreads();  // S1(3t)
        // waves 2-3: issue stale h1(t-1) loads for P2 (visible: waves 0-1 polled >=3t before S1)
        if (wave >= 2 && t < S_) {
            const bf16_t* h1p = h1b + (size_t)pbuf * BH + (size_t)b_ * H_ + (wave - 2) * 256 + quad * 8;
#pragma unroll
            for (int ki = 0; ki < 8; ++ki) pre[ki] = ld_slab(h1p + ki * 32);
        }
        // ---- P1 epilogue (all 256 threads) ----
        {
            if (t < S_) {
                float v = red[p1][0][0][er][ej] + red[p1][1][0][er][ej] +
                          red[p1][2][0][er][ej] + red[p1][3][0][er][ej];
                float vv = fmaxf(v + (t == 0 ? bias1t0j : bias1j), 0.f);
                st_bf16(&outb[(size_t)(g * 16 + er) * H_ + wg * 16 + ej], vv);
                asm volatile("s_waitcnt vmcnt(0)" ::: "memory");
                if (lane == 0)
                    __hip_atomic_store(&fb[wg * 16 + wave], n3t + 1, __ATOMIC_RELAXED,
                                       __HIP_MEMORY_SCOPE_AGENT);
            }
            if (t > 0 && ej < 4) {  // gen(t-1) -> d_out (off critical chain)
                float vg = red[p1][0][1][er][ej] + red[p1][1][1][er][ej] +
                           red[p1][2][1][er][ej] + red[p1][3][1][er][ej] + bgen;
                out[(size_t)(g * 16 + er) * (S_ * F_) + (size_t)(t - 1) * F_ + wg * 4 + ej] = vg;
            }
        }
        if (t == S_) break;

        // ================= P2 MFMA: gates1 = [out(t) | h1(t-1)] @ W2 =================
        {
            f32x4 ac[4];
#pragma unroll
            for (int q_ = 0; q_ < 4; ++q_) ac[q_] = (f32x4){0.f, 0.f, 0.f, 0.f};
            if (wave < 2) {
                flag_wait(fb, lane, n3t + 1);  // out(t) fresh
                const bf16_t* asrc = outb + (size_t)b_ * H_ + wave * 256 + quad * 8;
                bf16x8 aa[8];
#pragma unroll
                for (int ki = 0; ki < 8; ++ki) aa[ki] = ld_slab(asrc + ki * 32);
#pragma unroll
                for (int ki = 0; ki < 8; ++ki)
#pragma unroll
                    for (int gt = 0; gt < 4; ++gt)
                        ac[gt] = __builtin_amdgcn_mfma_f32_16x16x32_bf16(aa[ki], fr2[ki * 4 + gt], ac[gt], 0, 0, 0);
            } else {
#pragma unroll
                for (int ki = 0; ki < 8; ++ki)
#pragma unroll
                    for (int gt = 0; gt < 4; ++gt)
                        ac[gt] = __builtin_amdgcn_mfma_f32_16x16x32_bf16(pre[ki], fr2[ki * 4 + gt], ac[gt], 0, 0, 0);
            }
#pragma unroll
            for (int gt = 0; gt < 4; ++gt)
#pragma unroll
                for (int i = 0; i < 4; ++i) red[p2][wave][gt][quad * 4 + i][row16] = ac[gt][i];
        }
        __syncthreads();  // S1(3t+1)
        // waves 2-3: issue stale h2(t-1) loads for P3
        if (wave >= 2) {
            const bf16_t* h2s = h2b + (size_t)pbuf * BH + (size_t)b_ * H_ + (wave - 2) * 256 + quad * 8;
#pragma unroll
            for (int ki = 0; ki < 8; ++ki) pre[ki] = ld_slab(h2s + ki * 32);
        }
        // ---- P2 epilogue ----
        {
            float gi = red[p2][0][0][er][ej] + red[p2][1][0][er][ej] + red[p2][2][0][er][ej] +
                       red[p2][3][0][er][ej] + bi1;
            float gf = red[p2][0][1][er][ej] + red[p2][1][1][er][ej] + red[p2][2][1][er][ej] +
                       red[p2][3][1][er][ej] + bf1;
            float gg = red[p2][0][2][er][ej] + red[p2][1][2][er][ej] + red[p2][2][2][er][ej] +
                       red[p2][3][2][er][ej] + bg1;
            float go = red[p2][0][3][er][ej] + red[p2][1][3][er][ej] + red[p2][2][3][er][ej] +
                       red[p2][3][3][er][ej] + bo1;
            float cn = sigm(gf) * c1s + sigm(gi) * tanh_(gg);
            c1s = cn;
            float h = sigm(go) * tanh_(cn);
            st_bf16(&h1b[(size_t)cbuf * BH + (size_t)(g * 16 + er) * H_ + wg * 16 + ej], h);
            asm volatile("s_waitcnt vmcnt(0)" ::: "memory");
            if (lane == 0)
                __hip_atomic_store(&fb[wg * 16 + wave], n3t + 2, __ATOMIC_RELAXED,
                                   __HIP_MEMORY_SCOPE_AGENT);
            if (t == S_ - 1) {
                out[HO1 + (size_t)(g * 16 + er) * H_ + wg * 16 + ej] = h;
                out[CO1 + (size_t)(g * 16 + er) * H_ + wg * 16 + ej] = cn;
            }
        }

        // ================= P3 MFMA: gates2 = [h1(t) | h2(t-1)] @ W3 =================
        {
            f32x4 ac[4];
#pragma unroll
            for (int q_ = 0; q_ < 4; ++q_) ac[q_] = (f32x4){0.f, 0.f, 0.f, 0.f};
            if (wave < 2) {
                flag_wait(fb, lane, n3t + 2);  // h1(t) fresh
                const bf16_t* asrc = h1b + (size_t)cbuf * BH + (size_t)b_ * H_ + wave * 256 + quad * 8;
                bf16x8 aa[8];
#pragma unroll
                for (int ki = 0; ki < 8; ++ki) aa[ki] = ld_slab(asrc + ki * 32);
#pragma unroll
                for (int ki = 0; ki < 8; ++ki)
#pragma unroll
                    for (int gt = 0; gt < 4; ++gt)
                        ac[gt] = __builtin_amdgcn_mfma_f32_16x16x32_bf16(aa[ki], fr3[ki * 4 + gt], ac[gt], 0, 0, 0);
            } else {
#pragma unroll
                for (int ki = 0; ki < 8; ++ki)
#pragma unroll
                    for (int gt = 0; gt < 4; ++gt)
                        ac[gt] = __builtin_amdgcn_mfma_f32_16x16x32_bf16(pre[ki], fr3[ki * 4 + gt], ac[gt], 0, 0, 0);
            }
#pragma unroll
            for (int gt = 0; gt < 4; ++gt)
#pragma unroll
                for (int i = 0; i < 4; ++i) red[p3][wave][gt][quad * 4 + i][row16] = ac[gt][i];
        }
        __syncthreads();  // S1(3t+2)
        // waves 2-3: prefetch x(t+1) (plain cached loads, read-only input)
        if (wave >= 2) {
            const int tn = (t + 1 < S_) ? (t + 1) : (S_ - 1);
            const float* xp = x + ((size_t)b_ * S_ + tn) * F_ + (wave - 2) * 64 + quad * 8;
#pragma unroll
            for (int ki = 0; ki < 2; ++ki) {
                f32x4 x0 = *(const f32x4*)(xp + ki * 32);
                f32x4 x1 = *(const f32x4*)(xp + ki * 32 + 4);
                bf16x8 a;
#pragma unroll
                for (int i = 0; i < 4; ++i) { a[i] = (bf16_t)x0[i]; a[4 + i] = (bf16_t)x1[i]; }
                xpre[ki] = a;
            }
        }
        // ---- P3 epilogue ----
        {
            float gi = red[p3][0][0][er][ej] + red[p3][1][0][er][ej] + red[p3][2][0][er][ej] +
                       red[p3][3][0][er][ej] + bi2;
            float gf = red[p3][0][1][er][ej] + red[p3][1][1][er][ej] + red[p3][2][1][er][ej] +
                       red[p3][3][1][er][ej] + bf2;
            float gg = red[p3][0][2][er][ej] + red[p3][1][2][er][ej] + red[p3][2][2][er][ej] +
                       red[p3][3][2][er][ej] + bg2;
            float go = red[p3][0][3][er][ej] + red[p3][1][3][er][ej] + red[p3][2][3][er][ej] +
                       red[p3][3][3][er][ej] + bo2;
            float cn = sigm(gf) * c2s + sigm(gi) * tanh_(gg);
            c2s = cn;
            float h = sigm(go) * tanh_(cn);
            st_bf16(&h2b[(size_t)cbuf * BH + (size_t)(g * 16 + er) * H_ + wg * 16 + ej], h);
            asm volatile("s_waitcnt vmcnt(0)" ::: "memory");
            if (lane == 0)
                __hip_atomic_store(&fb[wg * 16 + wave], n3t + 3, __ATOMIC_RELAXED,
                                   __HIP_MEMORY_SCOPE_AGENT);
            if (t == S_ - 1) {
                out[HO2 + (size_t)(g * 16 + er) * H_ + wg * 16 + ej] = h;
                out[CO2 + (size_t)(g * 16 + er) * H_ + wg * 16 + ej] = cn;
            }
        }
    }
}

extern "C" void kernel_launch(void* const* d_in, const int* in_sizes, int n_in, void* d_out,
                              int out_size, void* d_ws, size_t ws_size, hipStream_t stream) {
    const float* x = (const float*)d_in[0];
    const float* pg0 = (const float*)d_in[1];
    const float* h1i = (const float*)d_in[2];
    const float* c1i = (const float*)d_in[3];
    const float* h2i = (const float*)d_in[4];
    const float* c2i = (const float*)d_in[5];
    const float* Wfc1 = (const float*)d_in[6];
    const float* bfc1 = (const float*)d_in[7];
    const float* Wih1 = (const float*)d_in[8];
    const float* Whh1 = (const float*)d_in[9];
    const float* b1 = (const float*)d_in[10];
    const float* Wih2 = (const float*)d_in[11];
    const float* Whh2 = (const float*)d_in[12];
    const float* b2g = (const float*)d_in[13];
    const float* Wfc2 = (const float*)d_in[14];
    const float* bfc2 = (const float*)d_in[15];
    uint8_t* ws = (uint8_t*)d_ws;
    float* out = (float*)d_out;

    k_init<<<dim3(128), dim3(256), 0, stream>>>(pg0, h1i, h2i, ws);
    k_fuse<<<dim3(512), dim3(128), 0, stream>>>(Wfc1, bfc1, Wfc2, bfc2, ws);
    k_frags<<<dim3(2688), dim3(256), 0, stream>>>(Wfc1, Wih1, Whh1, Wih2, Whh2, Wfc2, ws);
    k_rnn<<<dim3(128), dim3(256), 0, stream>>>(x, c1i, c2i, bfc1, b1, b2g, bfc2, ws, out);
}